// Round 9
// baseline (123.425 us; speedup 1.0000x reference)
//
#include <hip/hip_runtime.h>
#include <hip/hip_bf16.h>

// RetinaNet loss, fused. A=196608 anchors, T=200 targets, C=21 classes.
// SETTLED (rounds 0-8): inputs fp32, labels int32, OUTPUT = 3x FLOAT32.
// Rounds 2-8 all computed correct values (wc=38.0, wr=1.25, total=39.25 on the
// comparison grid) but stored them as 2-byte bf16 into the 4-byte fp32 output
// buffer — flat[0] then read back as ~wc, making err == wr == 1.25 invariant
// under every numeric change. Fix: write float. Fast-math fp32 kernel (round-2
// structure, proven grid-equal to an fp64 transliteration in rounds 4-8).

#define CLASSES 21
#define TPB 256

__global__ void zero_kernel(float* __restrict__ accums) {
    if (threadIdx.x < 3) accums[threadIdx.x] = 0.0f;   // cls_sum, reg_sum, pos_cnt
}

__global__ __launch_bounds__(TPB)
void main_kernel(const float* __restrict__ cls,
                 const float4* __restrict__ box,
                 const float4* __restrict__ anc,
                 const int* __restrict__ labels,
                 const float4* __restrict__ tbox,
                 float* __restrict__ accums,
                 int A, int T) {
    int a = blockIdx.x * blockDim.x + threadIdx.x;

    float cls_p = 0.0f, reg_p = 0.0f, pos_p = 0.0f;

    if (a < A) {
        float4 av = anc[a];                       // coalesced 16B/lane
        float ax1 = av.x, ay1 = av.y, ax2 = av.z, ay2 = av.w;
        float areaA = (ax2 - ax1) * (ay2 - ay1);  // anchor area

        // ---- IoU max/argmax over T targets (cross-mult, no divides) ----
        float bI = 0.0f, bU = 1.0f;               // best inter / best union
        int bT = 0;
        #pragma unroll 4
        for (int t = 0; t < T; ++t) {
            float4 tv = tbox[t];                  // wave-uniform -> scalar loads
            float ta = (tv.z - tv.x) * (tv.w - tv.y);
            float lx = fmaxf(tv.x, ax1);
            float ly = fmaxf(tv.y, ay1);
            float rx = fminf(tv.z, ax2);
            float ry = fminf(tv.w, ay2);
            float w = fmaxf(rx - lx, 0.0f);
            float h = fmaxf(ry - ly, 0.0f);
            float inter = w * h;
            float uni = ta + areaA - inter;       // boxes valid => uni >= ~1e-4
            // iou_t > iou_best  <=>  inter*bU > bI*uni  (unions > 0)
            bool gt = inter * bU > bI * uni;
            bI = gt ? inter : bI;
            bU = gt ? uni : bU;
            bT = gt ? t : bT;
        }
        bool pos = (bI + bI) >= bU;               // max_iou >= 0.5

        // ---- focal loss over 21 classes ----
        // t=0: f0(x)=0.75*s(x)^2*softplus(x);  t=1: (1/3)*f0(-x)
        int hot = pos ? labels[bT] : 0;           // background one-hot = class 0
        const float* crow = cls + (size_t)a * CLASSES;
        float csum = 0.0f;
        #pragma unroll
        for (int j = 0; j < CLASSES; ++j) {
            float x = crow[j];
            float y = (j == hot) ? -x : x;
            float em = __expf(-fabsf(y));                     // (0,1], overflow-free
            float sp = fmaxf(y, 0.0f) + __logf(1.0f + em);    // softplus(y)
            float r1 = __builtin_amdgcn_rcpf(1.0f + em);      // arg in [1,2]
            float sg = (y >= 0.0f) ? r1 : em * r1;            // sigmoid(y)
            float f = sg * sg * sp;
            csum = fmaf(f, (j == hot) ? (1.0f / 3.0f) : 1.0f, csum);
        }
        cls_p = csum * 0.75f;

        // ---- reg loss (positives only, ~14%) ----
        if (pos) {
            pos_p = 1.0f;
            float4 bv = box[a];
            float4 tv = tbox[bT];
            float aw = ax2 - ax1, ah = ay2 - ay1;
            float acx = (ax1 + ax2) * 0.5f, acy = (ay1 + ay2) * 0.5f;
            float ep0 = ((bv.x + bv.z) * 0.5f - acx) / aw;
            float ep1 = ((bv.y + bv.w) * 0.5f - acy) / ah;
            float ep2 = __logf((bv.z - bv.x) / aw);
            float ep3 = __logf((bv.w - bv.y) / ah);
            float et0 = ((tv.x + tv.z) * 0.5f - acx) / aw;
            float et1 = ((tv.y + tv.w) * 0.5f - acy) / ah;
            float et2 = __logf((tv.z - tv.x) / aw);
            float et3 = __logf((tv.w - tv.y) / ah);
            float r = 0.0f, d;
            d = fabsf(ep0 - et0); r += (d < 1.0f) ? 0.5f * d * d : d - 0.5f;
            d = fabsf(ep1 - et1); r += (d < 1.0f) ? 0.5f * d * d : d - 0.5f;
            d = fabsf(ep2 - et2); r += (d < 1.0f) ? 0.5f * d * d : d - 0.5f;
            d = fabsf(ep3 - et3); r += (d < 1.0f) ? 0.5f * d * d : d - 0.5f;
            reg_p = r;
        }
    }

    // ---- block reduction: wave shuffle -> LDS -> one atomic triple / block ----
    #pragma unroll
    for (int off = 32; off > 0; off >>= 1) {
        cls_p += __shfl_down(cls_p, off, 64);
        reg_p += __shfl_down(reg_p, off, 64);
        pos_p += __shfl_down(pos_p, off, 64);
    }
    __shared__ float red[3][TPB / 64];
    int wave = threadIdx.x >> 6;
    int lane = threadIdx.x & 63;
    if (lane == 0) {
        red[0][wave] = cls_p;
        red[1][wave] = reg_p;
        red[2][wave] = pos_p;
    }
    __syncthreads();
    if (threadIdx.x == 0) {
        float c = 0.0f, r = 0.0f, p = 0.0f;
        #pragma unroll
        for (int wv = 0; wv < TPB / 64; ++wv) {
            c += red[0][wv]; r += red[1][wv]; p += red[2][wv];
        }
        atomicAdd(&accums[0], c);
        atomicAdd(&accums[1], r);
        atomicAdd(&accums[2], p);
    }
}

// ---- finalize: FLOAT32 output (the round-0..8 bug was bf16 stores here) ----
__global__ void fin_kernel(const float* __restrict__ accums,
                           float* __restrict__ out) {
    float cls_sum = accums[0];
    float reg_sum = accums[1];
    float cnt = accums[2];
    float norm = fmaxf(cnt, 1.0f);
    float wc = cls_sum / norm;
    float wr = (cnt > 0.0f) ? reg_sum / (norm * 4.0f) : 0.0f;
    out[0] = wc + wr;
    out[1] = wc;
    out[2] = wr;
}

extern "C" void kernel_launch(void* const* d_in, const int* in_sizes, int n_in,
                              void* d_out, int out_size, void* d_ws, size_t ws_size,
                              hipStream_t stream) {
    const float* cls  = (const float*)d_in[0];   // [A,21] f32 classification_preds
    const float4* box = (const float4*)d_in[1];  // [A,4]  f32 boxes_preds
    const float4* anc = (const float4*)d_in[2];  // [A,4]  f32 anchors
    const float4* tb  = (const float4*)d_in[3];  // [T,4]  f32 target_boxes
    const int* tl     = (const int*)d_in[4];     // [T]    int32 target_labels

    int A = in_sizes[0] / CLASSES;               // 196608
    int T = in_sizes[4];                         // 200

    float* accums = (float*)d_ws;                // 12 bytes

    zero_kernel<<<1, 64, 0, stream>>>(accums);

    int main_blocks = (A + TPB - 1) / TPB;
    main_kernel<<<main_blocks, TPB, 0, stream>>>(cls, box, anc, tl, tb,
                                                 accums, A, T);

    fin_kernel<<<1, 1, 0, stream>>>(accums, (float*)d_out);
}

// Round 10
// 106.433 us; speedup vs baseline: 1.1597x; 1.1597x over previous
//
#include <hip/hip_runtime.h>
#include <hip/hip_bf16.h>

// RetinaNet loss, fused. A=196608, T=200, C=21. Inputs fp32, labels int32,
// out 3x fp32. R9 was latency-bound: 768 blocks -> 12 waves/CU cap, VALUBusy 45%.
// R10: quad-per-anchor split (4x waves), LDS-staged targets, packed-int argmax,
// block partials + tiny fin kernel (no atomics, no zero kernel).

#define CLASSES 21
#define TPB 256
#define APB 64            // anchors per block (TPB/4)
#define MAXT 256          // LDS capacity for targets (T=200)

__global__ __launch_bounds__(TPB)
void main_kernel(const float* __restrict__ cls,
                 const float4* __restrict__ box,
                 const float4* __restrict__ anc,
                 const int* __restrict__ labels,
                 const float4* __restrict__ tbox,
                 float* __restrict__ pc,    // per-block partial cls
                 float* __restrict__ pr,    // per-block partial reg
                 float* __restrict__ pp,    // per-block partial pos count
                 int A, int T) {
    __shared__ float4 s_tb[MAXT];
    __shared__ float  s_ta[MAXT];

    int tid = threadIdx.x;
    // ---- stage targets + areas in LDS (once per block) ----
    for (int t = tid; t < T; t += TPB) {
        float4 v = tbox[t];
        s_tb[t] = v;
        s_ta[t] = (v.z - v.x) * (v.w - v.y);
    }
    __syncthreads();

    int p = tid & 3;                       // lane within quad
    int a = blockIdx.x * APB + (tid >> 2); // anchor for this quad

    float cls_p = 0.0f, reg_p = 0.0f, pos_p = 0.0f;
    float ax1 = 0.f, ay1 = 0.f, ax2 = 0.f, ay2 = 0.f;
    float bIou = 0.0f;
    int bKey = 0;

    if (a < A) {
        float4 av = anc[a];
        ax1 = av.x; ay1 = av.y; ax2 = av.z; ay2 = av.w;
        float areaA = (ax2 - ax1) * (ay2 - ay1);

        // ---- IoU over strided targets: t = p, p+4, ... (50 iters) ----
        for (int t = p; t < T; t += 4) {
            float4 tv = s_tb[t];
            float ta = s_ta[t];
            float lx = fmaxf(tv.x, ax1);
            float ly = fmaxf(tv.y, ay1);
            float rx = fminf(tv.z, ax2);
            float ry = fminf(tv.w, ay2);
            float w = fmaxf(rx - lx, 0.0f);
            float h = fmaxf(ry - ly, 0.0f);
            float inter = w * h;
            float uni = (ta + areaA) - inter;          // >= 1e-4 by construction
            float iou = inter * __builtin_amdgcn_rcpf(uni);
            bIou = fmaxf(bIou, iou);
            // packed argmax key: high 24 bits = iou (>=0, monotonic as int),
            // low 8 bits = 255-t => ties pick smallest t (first-max, like np)
            int key = (__float_as_int(iou) & 0xFFFFFF00) | (255 - t);
            bKey = max(bKey, key);
        }
    }

    // ---- quad reduction (lanes 4q..4q+3 share an anchor) ----
    bKey = max(bKey, __shfl_xor(bKey, 1, 64));
    bKey = max(bKey, __shfl_xor(bKey, 2, 64));
    bIou = fmaxf(bIou, __shfl_xor(bIou, 1, 64));
    bIou = fmaxf(bIou, __shfl_xor(bIou, 2, 64));

    if (a < A) {
        int bT = 255 - (bKey & 0xFF);
        bool pos = bIou >= 0.5f;

        // ---- focal loss, classes split across the quad (6/5/5/5) ----
        int hot = pos ? labels[bT] : 0;
        const float* crow = cls + (size_t)a * CLASSES;
        float csum = 0.0f;
        #pragma unroll
        for (int k = 0; k < 6; ++k) {
            int j = p + 4 * k;
            if (j < CLASSES) {
                float x = crow[j];
                float y = (j == hot) ? -x : x;
                float em = __expf(-fabsf(y));                  // (0,1]
                float sp = fmaxf(y, 0.0f) + __logf(1.0f + em); // softplus(y)
                float r1 = __builtin_amdgcn_rcpf(1.0f + em);
                float sg = (y >= 0.0f) ? r1 : em * r1;         // sigmoid(y)
                float f = sg * sg * sp;
                csum = fmaf(f, (j == hot) ? (1.0f / 3.0f) : 1.0f, csum);
            }
        }
        cls_p = csum * 0.75f;

        // ---- reg loss: lane 0 of quad only, positives only (~14%) ----
        if (pos && p == 0) {
            pos_p = 1.0f;
            float4 bv = box[a];
            float4 tv = s_tb[bT];
            float aw = ax2 - ax1, ah = ay2 - ay1;
            float acx = (ax1 + ax2) * 0.5f, acy = (ay1 + ay2) * 0.5f;
            float ep0 = ((bv.x + bv.z) * 0.5f - acx) / aw;
            float ep1 = ((bv.y + bv.w) * 0.5f - acy) / ah;
            float ep2 = __logf((bv.z - bv.x) / aw);
            float ep3 = __logf((bv.w - bv.y) / ah);
            float et0 = ((tv.x + tv.z) * 0.5f - acx) / aw;
            float et1 = ((tv.y + tv.w) * 0.5f - acy) / ah;
            float et2 = __logf((tv.z - tv.x) / aw);
            float et3 = __logf((tv.w - tv.y) / ah);
            float r = 0.0f, d;
            d = fabsf(ep0 - et0); r += (d < 1.0f) ? 0.5f * d * d : d - 0.5f;
            d = fabsf(ep1 - et1); r += (d < 1.0f) ? 0.5f * d * d : d - 0.5f;
            d = fabsf(ep2 - et2); r += (d < 1.0f) ? 0.5f * d * d : d - 0.5f;
            d = fabsf(ep3 - et3); r += (d < 1.0f) ? 0.5f * d * d : d - 0.5f;
            reg_p = r;
        }
    }

    // ---- block reduction: wave shuffle -> LDS -> per-block partial ----
    #pragma unroll
    for (int off = 32; off > 0; off >>= 1) {
        cls_p += __shfl_down(cls_p, off, 64);
        reg_p += __shfl_down(reg_p, off, 64);
        pos_p += __shfl_down(pos_p, off, 64);
    }
    __shared__ float red[3][TPB / 64];
    int wave = tid >> 6;
    int lane = tid & 63;
    if (lane == 0) {
        red[0][wave] = cls_p;
        red[1][wave] = reg_p;
        red[2][wave] = pos_p;
    }
    __syncthreads();
    if (tid == 0) {
        float c = 0.0f, r = 0.0f, q = 0.0f;
        #pragma unroll
        for (int wv = 0; wv < TPB / 64; ++wv) {
            c += red[0][wv]; r += red[1][wv]; q += red[2][wv];
        }
        pc[blockIdx.x] = c;
        pr[blockIdx.x] = r;
        pp[blockIdx.x] = q;
    }
}

// ---- finalize: reduce per-block partials, write 3 fp32 ----
__global__ __launch_bounds__(TPB)
void fin_kernel(const float* __restrict__ pc,
                const float* __restrict__ pr,
                const float* __restrict__ pp,
                int nb, float* __restrict__ out) {
    int tid = threadIdx.x;
    float c = 0.0f, r = 0.0f, q = 0.0f;
    for (int i = tid; i < nb; i += TPB) {
        c += pc[i]; r += pr[i]; q += pp[i];
    }
    #pragma unroll
    for (int off = 32; off > 0; off >>= 1) {
        c += __shfl_down(c, off, 64);
        r += __shfl_down(r, off, 64);
        q += __shfl_down(q, off, 64);
    }
    __shared__ float red[3][TPB / 64];
    int wave = tid >> 6;
    int lane = tid & 63;
    if (lane == 0) { red[0][wave] = c; red[1][wave] = r; red[2][wave] = q; }
    __syncthreads();
    if (tid == 0) {
        float cs = 0.0f, rs = 0.0f, qs = 0.0f;
        #pragma unroll
        for (int wv = 0; wv < TPB / 64; ++wv) {
            cs += red[0][wv]; rs += red[1][wv]; qs += red[2][wv];
        }
        float norm = fmaxf(qs, 1.0f);
        float wc = cs / norm;
        float wr = (qs > 0.0f) ? rs / (norm * 4.0f) : 0.0f;
        out[0] = wc + wr;
        out[1] = wc;
        out[2] = wr;
    }
}

extern "C" void kernel_launch(void* const* d_in, const int* in_sizes, int n_in,
                              void* d_out, int out_size, void* d_ws, size_t ws_size,
                              hipStream_t stream) {
    const float* cls  = (const float*)d_in[0];   // [A,21] f32 classification_preds
    const float4* box = (const float4*)d_in[1];  // [A,4]  f32 boxes_preds
    const float4* anc = (const float4*)d_in[2];  // [A,4]  f32 anchors
    const float4* tb  = (const float4*)d_in[3];  // [T,4]  f32 target_boxes
    const int* tl     = (const int*)d_in[4];     // [T]    int32 target_labels

    int A = in_sizes[0] / CLASSES;               // 196608
    int T = in_sizes[4];                         // 200 (fits MAXT)

    int nb = (A + APB - 1) / APB;                // 3072 blocks
    float* pc = (float*)d_ws;                    // [nb]
    float* pr = pc + nb;                         // [nb]
    float* pp = pr + nb;                         // [nb]  (3*3072*4 = 36 KB << ws)

    main_kernel<<<nb, TPB, 0, stream>>>(cls, box, anc, tl, tb, pc, pr, pp, A, T);
    fin_kernel<<<1, TPB, 0, stream>>>(pc, pr, pp, nb, (float*)d_out);
}

// Round 11
// 105.507 us; speedup vs baseline: 1.1698x; 1.0088x over previous
//
#include <hip/hip_runtime.h>
#include <hip/hip_bf16.h>

// RetinaNet loss, fused. A=196608, T=200, C=21. Inputs fp32, labels int32,
// out 3x fp32. R10 post-mortem: main ~40us; model says LDS-issue floor 12us
// (A*T/64 ds_read_b128 x 12cyc / 256CU) + ~9us VALU overlapped. R11 cuts:
// (1) no s_ta array (area inline, kills the b32 LDS read),
// (2) no in-loop v_rcp (quarter-rate): cross-mult argmax, exact,
// (3) __launch_bounds__(256,8) -> 32 waves/CU (kernel is ~30 VGPR).

#define CLASSES 21
#define TPB 256
#define APB 64            // anchors per block (TPB/4)
#define MAXT 256          // LDS capacity for targets (T=200)

__global__ __launch_bounds__(TPB, 8)
void main_kernel(const float* __restrict__ cls,
                 const float4* __restrict__ box,
                 const float4* __restrict__ anc,
                 const int* __restrict__ labels,
                 const float4* __restrict__ tbox,
                 float* __restrict__ pc,    // per-block partial cls
                 float* __restrict__ pr,    // per-block partial reg
                 float* __restrict__ pp,    // per-block partial pos count
                 int A, int T) {
    __shared__ float4 s_tb[MAXT];

    int tid = threadIdx.x;
    // ---- stage targets in LDS (once per block) ----
    for (int t = tid; t < T; t += TPB) {
        s_tb[t] = tbox[t];
    }
    __syncthreads();

    int p = tid & 3;                       // lane within quad
    int a = blockIdx.x * APB + (tid >> 2); // anchor for this quad

    float cls_p = 0.0f, reg_p = 0.0f, pos_p = 0.0f;
    float ax1 = 0.f, ay1 = 0.f, ax2 = 0.f, ay2 = 0.f;
    float bI = 0.0f, bU = 1.0f;            // best inter / best union (cross-mult)
    int bT = 0;

    if (a < A) {
        float4 av = anc[a];
        ax1 = av.x; ay1 = av.y; ax2 = av.z; ay2 = av.w;
        float areaA = (ax2 - ax1) * (ay2 - ay1);

        // ---- IoU argmax over strided targets t = p, p+4, ... (50 iters) ----
        #pragma unroll 2
        for (int t = p; t < T; t += 4) {
            float4 tv = s_tb[t];
            float ta = (tv.z - tv.x) * (tv.w - tv.y);   // area inline (3 VALU)
            float lx = fmaxf(tv.x, ax1);
            float ly = fmaxf(tv.y, ay1);
            float rx = fminf(tv.z, ax2);
            float ry = fminf(tv.w, ay2);
            float w = fmaxf(rx - lx, 0.0f);
            float h = fmaxf(ry - ly, 0.0f);
            float inter = w * h;
            float uni = (ta + areaA) - inter;           // >= ~1e-4 (valid boxes)
            // iou_t > iou_best  <=>  inter*bU > bI*uni  (unions > 0), exact
            bool gt = inter * bU > bI * uni;
            bI = gt ? inter : bI;
            bU = gt ? uni : bU;
            bT = gt ? t : bT;
        }
    }

    // ---- quad reduction (lanes 4q..4q+3 share an anchor), cross-mult ----
    #pragma unroll
    for (int d = 1; d <= 2; d <<= 1) {
        float oI = __shfl_xor(bI, d, 64);
        float oU = __shfl_xor(bU, d, 64);
        int   oT = __shfl_xor(bT, d, 64);
        bool gt = oI * bU > bI * oU;      // ties keep ours (nonzero exact ties
        bI = gt ? oI : bI;                // are measure-zero; zero-ties leave
        bU = gt ? oU : bU;                // pos=false where bT is unused)
        bT = gt ? oT : bT;
    }

    if (a < A) {
        bool pos = (bI + bI) >= bU;       // max_iou >= 0.5, division-free exact

        // ---- focal loss, classes split across the quad (6/5/5/5) ----
        int hot = pos ? labels[bT] : 0;
        const float* crow = cls + (size_t)a * CLASSES;
        float csum = 0.0f;
        #pragma unroll
        for (int k = 0; k < 6; ++k) {
            int j = p + 4 * k;
            if (j < CLASSES) {
                float x = crow[j];
                float y = (j == hot) ? -x : x;
                float em = __expf(-fabsf(y));                  // (0,1]
                float sp = fmaxf(y, 0.0f) + __logf(1.0f + em); // softplus(y)
                float r1 = __builtin_amdgcn_rcpf(1.0f + em);
                float sg = (y >= 0.0f) ? r1 : em * r1;         // sigmoid(y)
                float f = sg * sg * sp;
                csum = fmaf(f, (j == hot) ? (1.0f / 3.0f) : 1.0f, csum);
            }
        }
        cls_p = csum * 0.75f;

        // ---- reg loss: lane 0 of quad only, positives only (~14%) ----
        if (pos && p == 0) {
            pos_p = 1.0f;
            float4 bv = box[a];
            float4 tv = s_tb[bT];
            float aw = ax2 - ax1, ah = ay2 - ay1;
            float acx = (ax1 + ax2) * 0.5f, acy = (ay1 + ay2) * 0.5f;
            float ep0 = ((bv.x + bv.z) * 0.5f - acx) / aw;
            float ep1 = ((bv.y + bv.w) * 0.5f - acy) / ah;
            float ep2 = __logf((bv.z - bv.x) / aw);
            float ep3 = __logf((bv.w - bv.y) / ah);
            float et0 = ((tv.x + tv.z) * 0.5f - acx) / aw;
            float et1 = ((tv.y + tv.w) * 0.5f - acy) / ah;
            float et2 = __logf((tv.z - tv.x) / aw);
            float et3 = __logf((tv.w - tv.y) / ah);
            float r = 0.0f, d;
            d = fabsf(ep0 - et0); r += (d < 1.0f) ? 0.5f * d * d : d - 0.5f;
            d = fabsf(ep1 - et1); r += (d < 1.0f) ? 0.5f * d * d : d - 0.5f;
            d = fabsf(ep2 - et2); r += (d < 1.0f) ? 0.5f * d * d : d - 0.5f;
            d = fabsf(ep3 - et3); r += (d < 1.0f) ? 0.5f * d * d : d - 0.5f;
            reg_p = r;
        }
    }

    // ---- block reduction: wave shuffle -> LDS -> per-block partial ----
    #pragma unroll
    for (int off = 32; off > 0; off >>= 1) {
        cls_p += __shfl_down(cls_p, off, 64);
        reg_p += __shfl_down(reg_p, off, 64);
        pos_p += __shfl_down(pos_p, off, 64);
    }
    __shared__ float red[3][TPB / 64];
    int wave = tid >> 6;
    int lane = tid & 63;
    if (lane == 0) {
        red[0][wave] = cls_p;
        red[1][wave] = reg_p;
        red[2][wave] = pos_p;
    }
    __syncthreads();
    if (tid == 0) {
        float c = 0.0f, r = 0.0f, q = 0.0f;
        #pragma unroll
        for (int wv = 0; wv < TPB / 64; ++wv) {
            c += red[0][wv]; r += red[1][wv]; q += red[2][wv];
        }
        pc[blockIdx.x] = c;
        pr[blockIdx.x] = r;
        pp[blockIdx.x] = q;
    }
}

// ---- finalize: reduce per-block partials, write 3 fp32 ----
__global__ __launch_bounds__(TPB)
void fin_kernel(const float* __restrict__ pc,
                const float* __restrict__ pr,
                const float* __restrict__ pp,
                int nb, float* __restrict__ out) {
    int tid = threadIdx.x;
    float c = 0.0f, r = 0.0f, q = 0.0f;
    for (int i = tid; i < nb; i += TPB) {
        c += pc[i]; r += pr[i]; q += pp[i];
    }
    #pragma unroll
    for (int off = 32; off > 0; off >>= 1) {
        c += __shfl_down(c, off, 64);
        r += __shfl_down(r, off, 64);
        q += __shfl_down(q, off, 64);
    }
    __shared__ float red[3][TPB / 64];
    int wave = tid >> 6;
    int lane = tid & 63;
    if (lane == 0) { red[0][wave] = c; red[1][wave] = r; red[2][wave] = q; }
    __syncthreads();
    if (tid == 0) {
        float cs = 0.0f, rs = 0.0f, qs = 0.0f;
        #pragma unroll
        for (int wv = 0; wv < TPB / 64; ++wv) {
            cs += red[0][wv]; rs += red[1][wv]; qs += red[2][wv];
        }
        float norm = fmaxf(qs, 1.0f);
        float wc = cs / norm;
        float wr = (qs > 0.0f) ? rs / (norm * 4.0f) : 0.0f;
        out[0] = wc + wr;
        out[1] = wc;
        out[2] = wr;
    }
}

extern "C" void kernel_launch(void* const* d_in, const int* in_sizes, int n_in,
                              void* d_out, int out_size, void* d_ws, size_t ws_size,
                              hipStream_t stream) {
    const float* cls  = (const float*)d_in[0];   // [A,21] f32 classification_preds
    const float4* box = (const float4*)d_in[1];  // [A,4]  f32 boxes_preds
    const float4* anc = (const float4*)d_in[2];  // [A,4]  f32 anchors
    const float4* tb  = (const float4*)d_in[3];  // [T,4]  f32 target_boxes
    const int* tl     = (const int*)d_in[4];     // [T]    int32 target_labels

    int A = in_sizes[0] / CLASSES;               // 196608
    int T = in_sizes[4];                         // 200 (fits MAXT)

    int nb = (A + APB - 1) / APB;                // 3072 blocks
    float* pc = (float*)d_ws;                    // [nb]
    float* pr = pc + nb;                         // [nb]
    float* pp = pr + nb;                         // [nb]  (36 KB << ws)

    main_kernel<<<nb, TPB, 0, stream>>>(cls, box, anc, tl, tb, pc, pr, pp, A, T);
    fin_kernel<<<1, TPB, 0, stream>>>(pc, pr, pp, nb, (float*)d_out);
}

// Round 12
// 104.387 us; speedup vs baseline: 1.1824x; 1.0107x over previous
//
#include <hip/hip_runtime.h>

// RetinaNet loss. A=196608, T=200, C=21; inputs fp32, labels int32, out 3x fp32.
// R11 post-mortem: quad-split LDS loop stuck at ~40us, insensitive to issue-count
// cuts -> abandon LDS feed. R12: T-split (G=4) IoU kernel with wave-uniform
// s_load target feed (pure-VALU inner loop, 17 ops/iter, no LDS/VMEM in loop),
// partials in ws; K2 combines + focal (LDS-staged cls tile) + reg; fin reduces.

#define CLASSES 21
#define TPB 256
#define G 4               // T-split chunks

// ---- prep: target areas (enables SGPR-held area; no scalar-float ALU on CDNA) ----
__global__ void prep_kernel(const float4* __restrict__ tb,
                            float* __restrict__ tarea, int T) {
    int t = blockIdx.x * blockDim.x + threadIdx.x;
    if (t < T) {
        float4 v = tb[t];
        tarea[t] = (v.z - v.x) * (v.w - v.y);   // fp32, same rounding as ref
    }
}

// ---- K1: partial IoU argmax per (chunk, anchor). Pure VALU + s_load. ----
__global__ __launch_bounds__(TPB)
void iou_kernel(const float4* __restrict__ anc,
                const float4* __restrict__ tbox,
                const float* __restrict__ tarea,
                float* __restrict__ pbI, float* __restrict__ pbU,
                int* __restrict__ pbT,
                int A, int T, int chunk) {
    int c  = blockIdx.x & (G - 1);
    int ab = blockIdx.x >> 2;
    int a  = ab * TPB + threadIdx.x;
    if (a >= A) return;

    float4 av = anc[a];                          // coalesced 16B/lane
    float areaA = (av.z - av.x) * (av.w - av.y);

    int t0 = c * chunk;
    int t1 = min(T, t0 + chunk);
    float bI = 0.0f, bU = 1.0f;                  // cross-mult running argmax
    int bT = t0;
    #pragma unroll 10
    for (int t = t0; t < t1; ++t) {
        float4 tv = tbox[t];                     // wave-uniform -> s_load_dwordx4
        float ta = tarea[t];                     // wave-uniform -> s_load_dword
        float lx = fmaxf(tv.x, av.x);
        float ly = fmaxf(tv.y, av.y);
        float rx = fminf(tv.z, av.z);
        float ry = fminf(tv.w, av.w);
        float w = fmaxf(rx - lx, 0.0f);
        float h = fmaxf(ry - ly, 0.0f);
        float inter = w * h;
        float uni = (ta + areaA) - inter;        // SGPR+VGPR ok; >= ~1e-4 valid boxes
        bool gt = inter * bU > bI * uni;         // iou_t > iou_best, exact
        bI = gt ? inter : bI;
        bU = gt ? uni : bU;
        bT = gt ? t : bT;
    }
    size_t o = (size_t)c * A + a;                // coalesced partial write
    pbI[o] = bI;
    pbU[o] = bU;
    pbT[o] = bT;
}

// ---- K2: combine partials (chunk order = first-max), focal + reg, block partials ----
__global__ __launch_bounds__(TPB)
void loss_kernel(const float* __restrict__ cls,
                 const float4* __restrict__ box,
                 const float4* __restrict__ anc,
                 const int* __restrict__ labels,
                 const float4* __restrict__ tbox,
                 const float* __restrict__ pbI, const float* __restrict__ pbU,
                 const int* __restrict__ pbT,
                 float* __restrict__ pc, float* __restrict__ pr,
                 float* __restrict__ pp,
                 int A) {
    __shared__ float s_cls[TPB * CLASSES];       // 21504 B tile
    int tid = threadIdx.x;
    int a = blockIdx.x * TPB + tid;

    // stage cls tile, coalesced float4 (tile base 16B-aligned: 5376 floats/tile)
    {
        const float4* g4 = (const float4*)(cls + (size_t)blockIdx.x * TPB * CLASSES);
        float4* s4 = (float4*)s_cls;
        int n4 = (TPB * CLASSES) / 4;            // 1344
        int lim4 = min(n4, (int)(((size_t)A * CLASSES - (size_t)blockIdx.x * TPB * CLASSES) / 4));
        for (int i = tid; i < lim4; i += TPB) s4[i] = g4[i];
    }
    __syncthreads();

    float cls_p = 0.0f, reg_p = 0.0f, pos_p = 0.0f;

    if (a < A) {
        // combine G partials in chunk order (strict > keeps earlier => first-max)
        float bI = 0.0f, bU = 1.0f;
        int bT = 0;
        #pragma unroll
        for (int c = 0; c < G; ++c) {
            size_t o = (size_t)c * A + a;
            float oI = pbI[o];
            float oU = pbU[o];
            int   oT = pbT[o];
            if (c == 0) { bI = oI; bU = oU; bT = oT; }
            else {
                bool gt = oI * bU > bI * oU;
                bI = gt ? oI : bI;
                bU = gt ? oU : bU;
                bT = gt ? oT : bT;
            }
        }
        bool pos = (bI + bI) >= bU;              // max_iou >= 0.5, division-free

        // ---- focal loss, 21 classes from LDS row (stride 21 -> 2-way, free) ----
        int hot = pos ? labels[bT] : 0;
        const float* crow = s_cls + tid * CLASSES;
        float csum = 0.0f;
        #pragma unroll
        for (int j = 0; j < CLASSES; ++j) {
            float x = crow[j];
            float y = (j == hot) ? -x : x;
            float em = __expf(-fabsf(y));                  // (0,1]
            float sp = fmaxf(y, 0.0f) + __logf(1.0f + em); // softplus(y)
            float r1 = __builtin_amdgcn_rcpf(1.0f + em);
            float sg = (y >= 0.0f) ? r1 : em * r1;         // sigmoid(y)
            float f = sg * sg * sp;
            csum = fmaf(f, (j == hot) ? (1.0f / 3.0f) : 1.0f, csum);
        }
        cls_p = csum * 0.75f;

        // ---- reg loss (positives only, ~14%) ----
        if (pos) {
            pos_p = 1.0f;
            float4 av = anc[a];
            float4 bv = box[a];
            float4 tv = tbox[bT];
            float aw = av.z - av.x, ah = av.w - av.y;
            float acx = (av.x + av.z) * 0.5f, acy = (av.y + av.w) * 0.5f;
            float ep0 = ((bv.x + bv.z) * 0.5f - acx) / aw;
            float ep1 = ((bv.y + bv.w) * 0.5f - acy) / ah;
            float ep2 = __logf((bv.z - bv.x) / aw);
            float ep3 = __logf((bv.w - bv.y) / ah);
            float et0 = ((tv.x + tv.z) * 0.5f - acx) / aw;
            float et1 = ((tv.y + tv.w) * 0.5f - acy) / ah;
            float et2 = __logf((tv.z - tv.x) / aw);
            float et3 = __logf((tv.w - tv.y) / ah);
            float r = 0.0f, d;
            d = fabsf(ep0 - et0); r += (d < 1.0f) ? 0.5f * d * d : d - 0.5f;
            d = fabsf(ep1 - et1); r += (d < 1.0f) ? 0.5f * d * d : d - 0.5f;
            d = fabsf(ep2 - et2); r += (d < 1.0f) ? 0.5f * d * d : d - 0.5f;
            d = fabsf(ep3 - et3); r += (d < 1.0f) ? 0.5f * d * d : d - 0.5f;
            reg_p = r;
        }
    }

    // ---- block reduction: wave shuffle -> LDS -> per-block partial ----
    #pragma unroll
    for (int off = 32; off > 0; off >>= 1) {
        cls_p += __shfl_down(cls_p, off, 64);
        reg_p += __shfl_down(reg_p, off, 64);
        pos_p += __shfl_down(pos_p, off, 64);
    }
    __shared__ float red[3][TPB / 64];
    int wave = tid >> 6;
    int lane = tid & 63;
    if (lane == 0) {
        red[0][wave] = cls_p;
        red[1][wave] = reg_p;
        red[2][wave] = pos_p;
    }
    __syncthreads();
    if (tid == 0) {
        float c = 0.0f, r = 0.0f, q = 0.0f;
        #pragma unroll
        for (int wv = 0; wv < TPB / 64; ++wv) {
            c += red[0][wv]; r += red[1][wv]; q += red[2][wv];
        }
        pc[blockIdx.x] = c;
        pr[blockIdx.x] = r;
        pp[blockIdx.x] = q;
    }
}

// ---- finalize: reduce per-block partials, write 3 fp32 ----
__global__ __launch_bounds__(TPB)
void fin_kernel(const float* __restrict__ pc,
                const float* __restrict__ pr,
                const float* __restrict__ pp,
                int nb, float* __restrict__ out) {
    int tid = threadIdx.x;
    float c = 0.0f, r = 0.0f, q = 0.0f;
    for (int i = tid; i < nb; i += TPB) {
        c += pc[i]; r += pr[i]; q += pp[i];
    }
    #pragma unroll
    for (int off = 32; off > 0; off >>= 1) {
        c += __shfl_down(c, off, 64);
        r += __shfl_down(r, off, 64);
        q += __shfl_down(q, off, 64);
    }
    __shared__ float red[3][TPB / 64];
    int wave = tid >> 6;
    int lane = tid & 63;
    if (lane == 0) { red[0][wave] = c; red[1][wave] = r; red[2][wave] = q; }
    __syncthreads();
    if (tid == 0) {
        float cs = 0.0f, rs = 0.0f, qs = 0.0f;
        #pragma unroll
        for (int wv = 0; wv < TPB / 64; ++wv) {
            cs += red[0][wv]; rs += red[1][wv]; qs += red[2][wv];
        }
        float norm = fmaxf(qs, 1.0f);
        float wc = cs / norm;
        float wr = (qs > 0.0f) ? rs / (norm * 4.0f) : 0.0f;
        out[0] = wc + wr;
        out[1] = wc;
        out[2] = wr;
    }
}

extern "C" void kernel_launch(void* const* d_in, const int* in_sizes, int n_in,
                              void* d_out, int out_size, void* d_ws, size_t ws_size,
                              hipStream_t stream) {
    const float* cls  = (const float*)d_in[0];   // [A,21] f32 classification_preds
    const float4* box = (const float4*)d_in[1];  // [A,4]  f32 boxes_preds
    const float4* anc = (const float4*)d_in[2];  // [A,4]  f32 anchors
    const float4* tb  = (const float4*)d_in[3];  // [T,4]  f32 target_boxes
    const int* tl     = (const int*)d_in[4];     // [T]    int32 target_labels

    int A = in_sizes[0] / CLASSES;               // 196608
    int T = in_sizes[4];                         // 200
    int chunk = (T + G - 1) / G;                 // 50

    // ws layout
    float* tarea = (float*)d_ws;                                     // [T]
    float* pbI   = (float*)((char*)d_ws + 4096);                     // [G*A]
    float* pbU   = pbI + (size_t)G * A;                              // [G*A]
    int*   pbT   = (int*)(pbU + (size_t)G * A);                      // [G*A]
    int nb2 = (A + TPB - 1) / TPB;                                   // 768
    float* pc = (float*)(pbT + (size_t)G * A);                       // [nb2]
    float* pr = pc + nb2;
    float* pp = pr + nb2;

    prep_kernel<<<(T + TPB - 1) / TPB, TPB, 0, stream>>>(tb, tarea, T);

    int nb1 = nb2 * G;                           // 3072
    iou_kernel<<<nb1, TPB, 0, stream>>>(anc, tb, tarea, pbI, pbU, pbT, A, T, chunk);

    loss_kernel<<<nb2, TPB, 0, stream>>>(cls, box, anc, tl, tb,
                                         pbI, pbU, pbT, pc, pr, pp, A);

    fin_kernel<<<1, TPB, 0, stream>>>(pc, pr, pp, nb2, (float*)d_out);
}